// Round 6
// baseline (237.941 us; speedup 1.0000x reference)
//
#include <hip/hip_runtime.h>
#include <hip/hip_cooperative_groups.h>

namespace cg = cooperative_groups;

#define NB 8
#define NA 9
#define HH 128
#define WW 128
#define NCELL (HH * WW)      // 16384
#define NTOT (NCELL * NA)    // 147456
#define PRE_K 2000
#define POST_K 300
#define CAP 4096
#define PARTS 18             // sweep blocks per batch
#define BLKS (NB * PARTS)    // 144 blocks
#define TPB 1024
#define NMS_TH 0.7f

// anchor widths/heights (exact integers); all anchor centers are 16*(w,h)+8
__constant__ float c_aw[NA] = {184.f, 368.f, 736.f, 128.f, 256.f, 512.f, 88.f, 176.f, 352.f};
__constant__ float c_ah[NA] = {96.f, 192.f, 384.f, 128.f, 256.f, 512.f, 176.f, 352.f, 704.f};

__device__ __forceinline__ unsigned int sortable(float s) {
    unsigned int u = __float_as_uint(s);
    return (u & 0x80000000u) ? ~u : (u | 0x80000000u);
}

__device__ __forceinline__ unsigned long long shflx64(unsigned long long v, int m) {
    return __shfl_xor(v, m, 64);
}

#define SHFL_STEP(J)                                                          \
    {                                                                         \
        int d_ = (J) >> 1;                                                    \
        bool keepMax = (((tid & d_) == 0) == (((2u * (unsigned)tid) & k) == 0)); \
        unsigned long long pa = shflx64(va, d_);                              \
        unsigned long long pb = shflx64(vb, d_);                              \
        va = keepMax ? (va > pa ? va : pa) : (va < pa ? va : pa);             \
        vb = keepMax ? (vb > pb ? vb : pb) : (vb < pb ? vb : pb);             \
    }
#define LOCAL_STEP()                                                          \
    {                                                                         \
        bool desc = (((2u * (unsigned)tid) & k) == 0);                        \
        unsigned long long lo = va < vb ? va : vb;                            \
        unsigned long long hi = va < vb ? vb : va;                            \
        va = desc ? hi : lo; vb = desc ? lo : hi;                             \
    }

__global__ __launch_bounds__(TPB) void fused_kernel(
    const float* __restrict__ scores, const float* __restrict__ deltas,
    const float* __restrict__ im_info,
    unsigned int* __restrict__ h0out, unsigned int* __restrict__ gh1,
    uint2* __restrict__ state0, unsigned int* __restrict__ state1,
    int* __restrict__ cnt, unsigned long long* __restrict__ buf,
    unsigned int* __restrict__ topidx, float4* __restrict__ props,
    unsigned long long* __restrict__ colm, float* __restrict__ out) {
    cg::grid_group grid = cg::this_grid();
    __shared__ __align__(16) unsigned char smem[33024];
    const int BID = blockIdx.x;
    const int tid = threadIdx.x;
    const int b = BID / PARTS;        // batch this block sweeps
    const int part = BID % PARTS;

    // ---- P0: load 8 scores into regs; 2048-bin (11-bit) LDS hist ----
    const float4* sp4 = (const float4*)(scores + (size_t)b * 18 * NCELL + (size_t)NA * NCELL);
    const int base4 = part * 2048;
    float4 v0 = sp4[base4 + tid];
    float4 v1 = sp4[base4 + 1024 + tid];
    unsigned int u0 = sortable(v0.x), u1 = sortable(v0.y), u2 = sortable(v0.z), u3 = sortable(v0.w);
    unsigned int u4 = sortable(v1.x), u5 = sortable(v1.y), u6 = sortable(v1.z), u7 = sortable(v1.w);
    {
        unsigned int* h2 = (unsigned int*)smem;
        h2[tid] = 0; h2[tid + 1024] = 0;
        __syncthreads();
        atomicAdd(&h2[u0 >> 21], 1u); atomicAdd(&h2[u1 >> 21], 1u);
        atomicAdd(&h2[u2 >> 21], 1u); atomicAdd(&h2[u3 >> 21], 1u);
        atomicAdd(&h2[u4 >> 21], 1u); atomicAdd(&h2[u5 >> 21], 1u);
        atomicAdd(&h2[u6 >> 21], 1u); atomicAdd(&h2[u7 >> 21], 1u);
        __syncthreads();
        h0out[(size_t)BID * 2048 + tid] = h2[tid];
        h0out[(size_t)BID * 2048 + tid + 1024] = h2[tid + 1024];
    }
    grid.sync();

    // ---- P1: select over 2048 bins, blocks 0..7; zero gh1/cnt ----
    if (BID < NB) {
        const int sb = BID;
        unsigned int* thr = (unsigned int*)smem;
        if (tid < 128) gh1[sb * 128 + tid] = 0;
        if (tid == 0) cnt[sb] = 0;
        unsigned int c0 = 0, c1 = 0;
        for (int p = 0; p < PARTS; ++p) {
            const unsigned int* hp = h0out + (size_t)(sb * PARTS + p) * 2048;
            uint2 v = *(const uint2*)&hp[2 * tid];
            c0 += v.x; c1 += v.y;
        }
        thr[tid] = c0 + c1;
        __syncthreads();
        for (int off = 1; off < 1024; off <<= 1) {
            unsigned int v = (tid + off < 1024) ? thr[tid + off] : 0u;
            __syncthreads();
            thr[tid] += v;
            __syncthreads();
        }
        unsigned int above = (tid < 1023) ? thr[tid + 1] : 0u;
        if (thr[tid] >= (unsigned)PRE_K && above < (unsigned)PRE_K) {
            if (above + c1 >= (unsigned)PRE_K)
                state0[sb] = make_uint2((unsigned)(2 * tid + 1), (unsigned)(PRE_K)-above);
            else
                state0[sb] = make_uint2((unsigned)(2 * tid), (unsigned)(PRE_K)-above - c1);
        }
    }
    grid.sync();

    // ---- P2: 7-bit refinement hist from registers ----
    {
        unsigned int* h128 = (unsigned int*)smem;
        if (tid < 128) h128[tid] = 0;
        __syncthreads();
        unsigned int piv = state0[b].x;
#define TEST(U) if (((U) >> 21) == piv) atomicAdd(&h128[((U) >> 14) & 127u], 1u);
        TEST(u0) TEST(u1) TEST(u2) TEST(u3) TEST(u4) TEST(u5) TEST(u6) TEST(u7)
#undef TEST
        __syncthreads();
        if (tid < 128 && h128[tid]) atomicAdd(&gh1[b * 128 + tid], h128[tid]);
    }
    grid.sync();

    // ---- P3: select over 128 sub-bins, blocks 0..7, wave 0 ----
    if (BID < NB && tid < 64) {
        const int sb = BID, lane = tid;
        unsigned int c0 = gh1[sb * 128 + 2 * lane];
        unsigned int c1 = gh1[sb * 128 + 2 * lane + 1];
        unsigned int sum = c0 + c1;
#pragma unroll
        for (int off = 1; off < 64; off <<= 1) {
            unsigned int v = __shfl_down(sum, off, 64);
            if (lane + off < 64) sum += v;
        }
        unsigned int above = __shfl_down(sum, 1, 64);
        if (lane == 63) above = 0;
        unsigned int need0 = state0[sb].y;
        if (sum >= need0 && above < need0) {
            unsigned int d = (above + c1 >= need0) ? (unsigned)(2 * lane + 1) : (unsigned)(2 * lane);
            state1[sb] = ((state0[sb].x << 7) | d) << 14;
        }
    }
    grid.sync();

    // ---- P4: gather from registers into LDS, 1 global atomic per block ----
    {
        unsigned long long* lbuf = (unsigned long long*)smem;   // 2048 entries
        int* lmisc = (int*)(smem + 16384);                      // [0]=lcnt [1]=gbase
        if (tid == 0) lmisc[0] = 0;
        __syncthreads();
        unsigned int P = state1[b];
        int e0 = (base4 + tid) * 4;
        int e1 = (base4 + 1024 + tid) * 4;
#define GATH(U, IDX4)                                                         \
        if ((U) >= P) {                                                       \
            int a_ = (IDX4) >> 14;                                            \
            int cell_ = (IDX4) & 16383;                                       \
            unsigned int i_ = (unsigned int)cell_ * 9u + (unsigned int)a_;    \
            int pos_ = atomicAdd(&lmisc[0], 1);                               \
            if (pos_ < 2048)                                                  \
                lbuf[pos_] = ((unsigned long long)(U) << 32) |                \
                             (unsigned long long)(0xFFFFFFFFu - i_);          \
        }
        GATH(u0, e0) GATH(u1, e0 + 1) GATH(u2, e0 + 2) GATH(u3, e0 + 3)
        GATH(u4, e1) GATH(u5, e1 + 1) GATH(u6, e1 + 2) GATH(u7, e1 + 3)
#undef GATH
        __syncthreads();
        if (tid == 0) lmisc[1] = atomicAdd(&cnt[b], lmisc[0]);
        __syncthreads();
        int m = min(lmisc[0], 2048), gb = lmisc[1];
        for (int t = tid; t < m; t += TPB) {
            int g = gb + t;
            if (g < CAP) buf[(size_t)b * CAP + g] = lbuf[t];
        }
    }
    grid.sync();

    // ---- P5: hybrid register/LDS bitonic sort (desc), blocks 0..7 ----
    if (BID < NB) {
        unsigned long long* s = (unsigned long long*)smem;
        int n = min(cnt[BID], CAP);
        const unsigned long long* src = buf + (size_t)BID * CAP;
        if (n <= 2048) {
            unsigned long long va = (2 * tid < n) ? src[2 * tid] : 0ULL;
            unsigned long long vb = (2 * tid + 1 < n) ? src[2 * tid + 1] : 0ULL;
#pragma unroll
            for (unsigned k = 2; k <= 128; k <<= 1) {
#pragma unroll
                for (unsigned j = k >> 1; j >= 2; j >>= 1) SHFL_STEP(j)
                LOCAL_STEP()
            }
            for (unsigned k = 256; k <= 2048; k <<= 1) {
                s[2 * tid] = va; s[2 * tid + 1] = vb;
                __syncthreads();
                for (unsigned j = k >> 1; j >= 128; j >>= 1) {
                    for (int t = tid; t < 2048; t += TPB) {
                        int ixj = t ^ (int)j;
                        if (ixj > t) {
                            unsigned long long x = s[t], y = s[ixj];
                            if ((((unsigned)t & k) == 0) ? (x < y) : (x > y)) { s[t] = y; s[ixj] = x; }
                        }
                    }
                    __syncthreads();
                }
                va = s[2 * tid]; vb = s[2 * tid + 1];
#pragma unroll
                for (unsigned j = 64; j >= 2; j >>= 1) SHFL_STEP(j)
                LOCAL_STEP()
            }
            s[2 * tid] = va; s[2 * tid + 1] = vb;
            __syncthreads();
        } else {
            for (int t = tid; t < CAP; t += TPB)
                s[t] = (t < n) ? src[t] : 0ULL;
            __syncthreads();
            for (int k = 2; k <= CAP; k <<= 1) {
                for (int j = k >> 1; j > 0; j >>= 1) {
                    for (int t = tid; t < CAP; t += TPB) {
                        int ixj = t ^ j;
                        if (ixj > t) {
                            unsigned long long x = s[t], y = s[ixj];
                            if (((t & k) == 0) ? (x < y) : (x > y)) { s[t] = y; s[ixj] = x; }
                        }
                    }
                    __syncthreads();
                }
            }
        }
        for (int r = tid; r < PRE_K; r += TPB)
            topidx[(size_t)BID * PRE_K + r] = 0xFFFFFFFFu - (unsigned int)(s[r] & 0xFFFFFFFFu);
    }
    grid.sync();

    // ---- P6: decode + clip, chip-wide (numerics identical to passing version) ----
    {
        int gid = BID * TPB + tid;
        if (gid < NB * PRE_K) {
            int db = gid / PRE_K;
            unsigned int i = topidx[gid];
            unsigned int cell = i / 9u;
            unsigned int a = i - cell * 9u;
            int wx = (int)(cell & 127u), hy = (int)(cell >> 7);
            const float* dp = deltas + (size_t)db * 36 * NCELL + (size_t)(4u * a) * NCELL +
                              (size_t)hy * WW + wx;
            float dx = dp[0];
            float dy = dp[NCELL];
            float dw = dp[2 * NCELL];
            float dh = dp[3 * NCELL];
            float W_ = c_aw[a], H_ = c_ah[a];
            float cx = (float)(16 * wx + 8), cy = (float)(16 * hy + 8);
            float px = __fadd_rn(__fmul_rn(dx, W_), cx);
            float py = __fadd_rn(__fmul_rn(dy, H_), cy);
            float pw = __fmul_rn((float)exp((double)dw), W_);
            float ph = __fmul_rn((float)exp((double)dh), H_);
            float hw = __fmul_rn(0.5f, pw), hh = __fmul_rn(0.5f, ph);
            float x1 = __fsub_rn(px, hw), y1 = __fsub_rn(py, hh);
            float x2 = __fadd_rn(px, hw), y2 = __fadd_rn(py, hh);
            float maxx = __fsub_rn(im_info[db * 3 + 1], 1.0f);
            float maxy = __fsub_rn(im_info[db * 3 + 0], 1.0f);
            x1 = fminf(fmaxf(x1, 0.0f), maxx);
            y1 = fminf(fmaxf(y1, 0.0f), maxy);
            x2 = fminf(fmaxf(x2, 0.0f), maxx);
            y2 = fminf(fmaxf(y2, 0.0f), maxy);
            props[gid] = make_float4(x1, y1, x2, y2);
        }
    }
    grid.sync();

    // ---- P7: NMS bitmask, column form; all boxes of a batch staged in LDS ----
    {
        float4* sbox = (float4*)smem;
        for (int p = BID; p < NB * 32; p += BLKS) {
            int pb = p >> 5, jT = p & 31;
            __syncthreads();
            for (int t = tid; t < PRE_K; t += TPB) sbox[t] = props[pb * PRE_K + t];
            __syncthreads();
            int jl = tid & 63, g = tid >> 6;   // 16 iT-groups
            int j = jT * 64 + jl;
            float4 jb = sbox[j];               // j>=PRE_K reads stale LDS; results unused
            float barea = __fmul_rn(__fsub_rn(jb.z, jb.x), __fsub_rn(jb.w, jb.y));
            for (int iT = g; iT <= jT; iT += 16) {
                unsigned long long m = 0ULL;
                int i0 = iT * 64;
#pragma unroll 8
                for (int ii = 0; ii < 64; ++ii) {
                    int i = i0 + ii;
                    if (i < j) {
                        float4 c = sbox[i0 + ii];
                        float aarea = __fmul_rn(__fsub_rn(c.z, c.x), __fsub_rn(c.w, c.y));
                        float xx1 = fmaxf(c.x, jb.x), yy1 = fmaxf(c.y, jb.y);
                        float xx2 = fminf(c.z, jb.z), yy2 = fminf(c.w, jb.w);
                        float iw = fmaxf(__fsub_rn(xx2, xx1), 0.0f);
                        float ih = fmaxf(__fsub_rn(yy2, yy1), 0.0f);
                        float inter = __fmul_rn(iw, ih);
                        float denom = __fadd_rn(__fsub_rn(__fadd_rn(aarea, barea), inter), 1e-9f);
                        float iou = __fdiv_rn(inter, denom);
                        if (iou > NMS_TH) m |= (1ULL << ii);
                    }
                }
                colm[((size_t)pb * 32 + iT) * 2048 + j] = m;
            }
        }
    }
    grid.sync();

    // ---- P8: greedy scan via ballots, blocks 0..7 ----
    if (BID >= NB) return;
    {
        unsigned long long* kw = (unsigned long long*)smem;       // 32 * 8B
        int* keeplist = (int*)(smem + 256);                       // 300 * 4B
        int* sctl = (int*)(smem + 256 + POST_K * 4);              // [0]=done [1]=total
        if (tid == 0) { sctl[0] = 0; sctl[1] = 0; }
        __syncthreads();
        const unsigned long long* cb = colm + (size_t)BID * 32 * 2048;
        int total = 0;
        for (int k = 0; k < 32; ++k) {
            if (tid < 64) {
                int lane = tid;
                int j = k * 64 + lane;
                unsigned long long d = 0;
                int w = 0;
                for (; w + 4 <= k; w += 4) {
                    unsigned long long a0 = cb[(size_t)(w + 0) * 2048 + j] & kw[w + 0];
                    unsigned long long a1 = cb[(size_t)(w + 1) * 2048 + j] & kw[w + 1];
                    unsigned long long a2 = cb[(size_t)(w + 2) * 2048 + j] & kw[w + 2];
                    unsigned long long a3 = cb[(size_t)(w + 3) * 2048 + j] & kw[w + 3];
                    d |= (a0 | a1) | (a2 | a3);
                }
                for (; w < k; ++w) d |= cb[(size_t)w * 2048 + j] & kw[w];
                unsigned long long diag = cb[(size_t)k * 2048 + j];
                bool alive_me = (d == 0ULL) && (j < PRE_K);
                unsigned long long alive = __ballot(alive_me);
                unsigned long long keptw = 0ULL;
                while (alive) {
                    int i = __builtin_ctzll(alive);
                    keptw |= (1ULL << i);
                    if (lane == 0 && total < POST_K) keeplist[total] = k * 64 + i;
                    total++;
                    if (total >= POST_K) break;
                    unsigned long long sup = __ballot(((diag >> i) & 1ULL) != 0ULL);
                    alive &= ~sup;
                    alive &= ~keptw;
                }
                if (lane == 0) {
                    kw[k] = keptw;
                    sctl[0] = (total >= POST_K) ? 1 : 0;
                    sctl[1] = total;
                }
            }
            __syncthreads();
            if (sctl[0]) break;
        }
        __syncthreads();
        int K = min(sctl[1], POST_K);
        const float4* bb = props + (size_t)BID * PRE_K;
        for (int r = tid; r < POST_K; r += TPB) {
            float4 v = make_float4(0.f, 0.f, 0.f, 0.f);
            if (r < K) v = bb[keeplist[r]];
            float* o = out + ((size_t)BID * POST_K + r) * 5;
            o[0] = (float)BID;
            o[1] = v.x;
            o[2] = v.y;
            o[3] = v.z;
            o[4] = v.w;
        }
    }
}

// ---------------- launcher ----------------
extern "C" void kernel_launch(void* const* d_in, const int* in_sizes, int n_in,
                              void* d_out, int out_size, void* d_ws, size_t ws_size,
                              hipStream_t stream) {
    const float* scores = (const float*)d_in[0];
    const float* deltas = (const float*)d_in[1];
    const float* im_info = (const float*)d_in[2];
    float* out = (float*)d_out;
    char* ws = (char*)d_ws;

    // workspace layout (bytes)
    unsigned int* h0out = (unsigned int*)(ws + 0);                 // 144*2048*4 = 1179648
    unsigned int* gh1 = (unsigned int*)(ws + 1179648);             // 4096
    uint2* state0 = (uint2*)(ws + 1183744);                        // 64
    unsigned int* state1 = (unsigned int*)(ws + 1183808);          // 64
    int* cnt = (int*)(ws + 1183872);                               // 64
    unsigned long long* buf = (unsigned long long*)(ws + 1183936); // 262144
    unsigned int* topidx = (unsigned int*)(ws + 1446080);          // 64000
    float4* props = (float4*)(ws + 1510080);                       // 256000
    unsigned long long* colm = (unsigned long long*)(ws + 1766080);// 4194304
    // total ≈ 5.96 MB; all consumed bytes written before read each call

    void* args[] = {(void*)&scores, (void*)&deltas, (void*)&im_info,
                    (void*)&h0out, (void*)&gh1, (void*)&state0, (void*)&state1,
                    (void*)&cnt, (void*)&buf, (void*)&topidx, (void*)&props,
                    (void*)&colm, (void*)&out};
    hipLaunchCooperativeKernel((void*)fused_kernel, dim3(BLKS), dim3(TPB),
                               args, 0, stream);
}

// Round 7
// 100.651 us; speedup vs baseline: 2.3640x; 2.3640x over previous
//
#include <hip/hip_runtime.h>

#define NB 8
#define NA 9
#define NCELL (128 * 128)    // 16384
#define NTOT (NCELL * NA)    // 147456
#define PRE_K 2000
#define POST_K 300
#define CAP2 8192            // coarse candidate cap per batch
#define PARTS 18             // sweep blocks per batch (1024 thr, 8192 elems each)
#define NMS_TH 0.7f

// anchor widths/heights (exact integers); all anchor centers are 16*(w,h)+8
__constant__ float c_aw[NA] = {184.f, 368.f, 736.f, 128.f, 256.f, 512.f, 88.f, 176.f, 352.f};
__constant__ float c_ah[NA] = {96.f, 192.f, 384.f, 128.f, 256.f, 512.f, 176.f, 352.f, 704.f};

__device__ __forceinline__ unsigned int sortable(float s) {
    unsigned int u = __float_as_uint(s);
    return (u & 0x80000000u) ? ~u : (u | 0x80000000u);
}

__device__ __forceinline__ unsigned long long shflx64(unsigned long long v, int m) {
    return __shfl_xor(v, m, 64);
}

// exact reference IoU decision for pair (i-box c, j-box jb); aarea=area(c), barea=area(jb)
__device__ __forceinline__ bool iou_gt(float4 c, float4 jb, float barea) {
    float aarea = __fmul_rn(__fsub_rn(c.z, c.x), __fsub_rn(c.w, c.y));
    float xx1 = fmaxf(c.x, jb.x), yy1 = fmaxf(c.y, jb.y);
    float xx2 = fminf(c.z, jb.z), yy2 = fminf(c.w, jb.w);
    float iw = fmaxf(__fsub_rn(xx2, xx1), 0.0f);
    float ih = fmaxf(__fsub_rn(yy2, yy1), 0.0f);
    float inter = __fmul_rn(iw, ih);
    float denom = __fadd_rn(__fsub_rn(__fadd_rn(aarea, barea), inter), 1e-9f);
    return __fdiv_rn(inter, denom) > NMS_TH;
}

// ---------- pass 0: 11-bit LDS histogram, per-block write-out ----------
// grid (PARTS, NB) x 1024; block covers 2048 float4 = 8192 elems
__global__ __launch_bounds__(1024) void hist0_kernel(const float* __restrict__ scores,
                                                     unsigned int* __restrict__ h0out) {
    __shared__ unsigned int h[2048];
    int b = blockIdx.y, tid = threadIdx.x;
    h[tid] = 0; h[tid + 1024] = 0;
    __syncthreads();
    const float4* sp4 = (const float4*)(scores + (size_t)b * 18 * NCELL + (size_t)NA * NCELL);
    int base4 = blockIdx.x * 2048;
#pragma unroll
    for (int e = 0; e < 2; ++e) {
        float4 v = sp4[base4 + e * 1024 + tid];
        atomicAdd(&h[sortable(v.x) >> 21], 1u);
        atomicAdd(&h[sortable(v.y) >> 21], 1u);
        atomicAdd(&h[sortable(v.z) >> 21], 1u);
        atomicAdd(&h[sortable(v.w) >> 21], 1u);
    }
    __syncthreads();
    unsigned int* o = h0out + ((size_t)(b * PARTS + blockIdx.x)) * 2048;
    o[tid] = h[tid];
    o[tid + 1024] = h[tid + 1024];
}

// ---------- select over 2048 bins (wave-level suffix scan); zero gh1 + cnt ----------
__global__ __launch_bounds__(1024) void select0_kernel(const unsigned int* __restrict__ h0out,
                                                       uint2* __restrict__ state0,
                                                       unsigned int* __restrict__ gh1,
                                                       int* __restrict__ cnt) {
    __shared__ unsigned int wpart[16], wexcl[16];
    __shared__ unsigned int thr[1024];
    int b = blockIdx.x, tid = threadIdx.x;
    int lane = tid & 63, wid = tid >> 6;
    if (tid < 128) gh1[b * 128 + tid] = 0;
    if (tid == 0) cnt[b] = 0;
    unsigned int c0 = 0, c1 = 0;
    for (int p = 0; p < PARTS; ++p) {
        const unsigned int* hp = h0out + ((size_t)(b * PARTS + p)) * 2048;
        uint2 v = *(const uint2*)&hp[2 * tid];
        c0 += v.x; c1 += v.y;
    }
    // in-wave inclusive suffix scan
    unsigned int sum = c0 + c1;
#pragma unroll
    for (int off = 1; off < 64; off <<= 1) {
        unsigned int v = __shfl_down(sum, off, 64);
        if (lane + off < 64) sum += v;
    }
    if (lane == 0) wpart[wid] = sum;
    __syncthreads();
    if (tid < 16) {
        unsigned int e = 0;
        for (int w = tid + 1; w < 16; ++w) e += wpart[w];
        wexcl[tid] = e;
    }
    __syncthreads();
    unsigned int self = sum + wexcl[wid];    // count(bins >= 2*tid)
    thr[tid] = self;
    __syncthreads();
    unsigned int above = (tid < 1023) ? thr[tid + 1] : 0u;  // count(bins >= 2*tid+2)
    if (self >= (unsigned)PRE_K && above < (unsigned)PRE_K) {
        if (above + c1 >= (unsigned)PRE_K)
            state0[b] = make_uint2((unsigned)(2 * tid + 1), (unsigned)(PRE_K)-above);
        else
            state0[b] = make_uint2((unsigned)(2 * tid), (unsigned)(PRE_K)-above - c1);
    }
}

// ---------- gather at coarse 11-bit pivot + 128-bin refinement hist ----------
// grid (PARTS, NB) x 1024
__global__ __launch_bounds__(1024) void gatherc_kernel(const float* __restrict__ scores,
                                                       const uint2* __restrict__ state0,
                                                       unsigned int* __restrict__ gh1,
                                                       int* __restrict__ cnt,
                                                       unsigned long long* __restrict__ buf) {
    __shared__ unsigned long long lbuf[2048];
    __shared__ unsigned int h128[128];
    __shared__ int lmisc[2];   // [0]=lcnt [1]=gbase
    int b = blockIdx.y, tid = threadIdx.x;
    if (tid < 128) h128[tid] = 0;
    if (tid == 0) lmisc[0] = 0;
    __syncthreads();
    unsigned int piv = state0[b].x;
    unsigned int P = piv << 21;          // coarse threshold (floor of pivot bin)
    const float4* sp4 = (const float4*)(scores + (size_t)b * 18 * NCELL + (size_t)NA * NCELL);
    int base4 = blockIdx.x * 2048;
#pragma unroll
    for (int e = 0; e < 2; ++e) {
        int t4 = base4 + e * 1024 + tid;
        float4 v = sp4[t4];
        float el[4] = {v.x, v.y, v.z, v.w};
#pragma unroll
        for (int j = 0; j < 4; ++j) {
            unsigned int u = sortable(el[j]);
            if (u >= P) {
                if ((u >> 21) == piv) atomicAdd(&h128[(u >> 14) & 127u], 1u);
                int idx4 = t4 * 4 + j;            // = a*16384 + cell (channel-major)
                int a = idx4 >> 14;
                int cell = idx4 & 16383;
                unsigned int i = (unsigned int)cell * 9u + (unsigned int)a;
                int pos = atomicAdd(&lmisc[0], 1);
                if (pos < 2048)
                    lbuf[pos] = ((unsigned long long)u << 32) |
                                (unsigned long long)(0xFFFFFFFFu - i);
            }
        }
    }
    __syncthreads();
    if (tid < 128 && h128[tid]) atomicAdd(&gh1[b * 128 + tid], h128[tid]);
    if (tid == 0) lmisc[1] = atomicAdd(&cnt[b], min(lmisc[0], 2048));
    __syncthreads();
    int m = min(lmisc[0], 2048), gb = lmisc[1];
    for (int t = tid; t < m; t += 1024) {
        int g = gb + t;
        if (g < CAP2) buf[(size_t)b * CAP2 + g] = lbuf[t];
    }
}

// ---------- per-batch: exact pivot + filter + hybrid sort + inline decode ----------
#define SHFL_STEP(J)                                                          \
    {                                                                         \
        int d_ = (J) >> 1;                                                    \
        bool keepMax = (((tid & d_) == 0) == (((2u * (unsigned)tid) & k) == 0)); \
        unsigned long long pa = shflx64(va, d_);                              \
        unsigned long long pb = shflx64(vb, d_);                              \
        va = keepMax ? (va > pa ? va : pa) : (va < pa ? va : pa);             \
        vb = keepMax ? (vb > pb ? vb : pb) : (vb < pb ? vb : pb);             \
    }
#define LOCAL_STEP()                                                          \
    {                                                                         \
        bool desc = (((2u * (unsigned)tid) & k) == 0);                        \
        unsigned long long lo = va < vb ? va : vb;                            \
        unsigned long long hi = va < vb ? vb : va;                            \
        va = desc ? hi : lo; vb = desc ? lo : hi;                             \
    }

__global__ __launch_bounds__(1024) void sortdec_kernel(const unsigned long long* __restrict__ buf,
                                                       const int* __restrict__ cnt,
                                                       const uint2* __restrict__ state0,
                                                       const unsigned int* __restrict__ gh1,
                                                       const float* __restrict__ deltas,
                                                       const float* __restrict__ im_info,
                                                       float4* __restrict__ props) {
    __shared__ unsigned long long s[4096];
    __shared__ unsigned int spiv;
    __shared__ int fcnt;
    int b = blockIdx.x, tid = threadIdx.x;
    if (tid == 0) fcnt = 0;
    // exact 18-bit pivot from refinement hist (wave 0) — same logic as old select1
    if (tid < 64) {
        int lane = tid;
        unsigned int c0 = gh1[b * 128 + 2 * lane];
        unsigned int c1 = gh1[b * 128 + 2 * lane + 1];
        unsigned int sum = c0 + c1;
#pragma unroll
        for (int off = 1; off < 64; off <<= 1) {
            unsigned int v = __shfl_down(sum, off, 64);
            if (lane + off < 64) sum += v;
        }
        unsigned int above = __shfl_down(sum, 1, 64);
        if (lane == 63) above = 0;
        unsigned int need0 = state0[b].y;
        if (sum >= need0 && above < need0) {
            unsigned int d = (above + c1 >= need0) ? (unsigned)(2 * lane + 1) : (unsigned)(2 * lane);
            spiv = ((state0[b].x << 7) | d) << 14;
        }
    }
    __syncthreads();
    unsigned int P = spiv;
    int n = min(cnt[b], CAP2);
    const unsigned long long* src = buf + (size_t)b * CAP2;
    for (int t = tid; t < n; t += 1024) {
        unsigned long long e = src[t];
        if ((unsigned int)(e >> 32) >= P) {
            int pos = atomicAdd(&fcnt, 1);
            if (pos < 4096) s[pos] = e;
        }
    }
    __syncthreads();
    int n2 = min(fcnt, 4096);
    int SZ = (n2 <= 2048) ? 2048 : 4096;
    for (int t = tid; t < SZ; t += 1024)
        if (t >= n2) s[t] = 0ULL;
    __syncthreads();
    if (SZ == 2048) {
        unsigned long long va = s[2 * tid], vb = s[2 * tid + 1];
#pragma unroll
        for (unsigned k = 2; k <= 128; k <<= 1) {
#pragma unroll
            for (unsigned j = k >> 1; j >= 2; j >>= 1) SHFL_STEP(j)
            LOCAL_STEP()
        }
        for (unsigned k = 256; k <= 2048; k <<= 1) {
            s[2 * tid] = va; s[2 * tid + 1] = vb;
            __syncthreads();
            for (unsigned j = k >> 1; j >= 128; j >>= 1) {
                for (int t = tid; t < 2048; t += 1024) {
                    int ixj = t ^ (int)j;
                    if (ixj > t) {
                        unsigned long long x = s[t], y = s[ixj];
                        if ((((unsigned)t & k) == 0) ? (x < y) : (x > y)) { s[t] = y; s[ixj] = x; }
                    }
                }
                __syncthreads();
            }
            va = s[2 * tid]; vb = s[2 * tid + 1];
#pragma unroll
            for (unsigned j = 64; j >= 2; j >>= 1) SHFL_STEP(j)
            LOCAL_STEP()
        }
        s[2 * tid] = va; s[2 * tid + 1] = vb;
        __syncthreads();
    } else {
        for (int k = 2; k <= 4096; k <<= 1) {
            for (int j = k >> 1; j > 0; j >>= 1) {
                for (int t = tid; t < 4096; t += 1024) {
                    int ixj = t ^ j;
                    if (ixj > t) {
                        unsigned long long x = s[t], y = s[ixj];
                        if (((t & k) == 0) ? (x < y) : (x > y)) { s[t] = y; s[ixj] = x; }
                    }
                }
                __syncthreads();
            }
        }
    }
    // inline decode + clip (numerics identical to passing version)
    float maxx = __fsub_rn(im_info[b * 3 + 1], 1.0f);
    float maxy = __fsub_rn(im_info[b * 3 + 0], 1.0f);
    const float* dbase = deltas + (size_t)b * 36 * NCELL;
    for (int r = tid; r < PRE_K; r += 1024) {
        unsigned int i = 0xFFFFFFFFu - (unsigned int)(s[r] & 0xFFFFFFFFu);
        unsigned int cell = i / 9u;
        unsigned int a = i - cell * 9u;
        int wx = (int)(cell & 127u), hy = (int)(cell >> 7);
        const float* dp = dbase + (size_t)(4u * a) * NCELL + (size_t)hy * 128 + wx;
        float dx = dp[0];
        float dy = dp[NCELL];
        float dw = dp[2 * NCELL];
        float dh = dp[3 * NCELL];
        float W_ = c_aw[a], H_ = c_ah[a];
        float cx = (float)(16 * wx + 8), cy = (float)(16 * hy + 8);
        float px = __fadd_rn(__fmul_rn(dx, W_), cx);
        float py = __fadd_rn(__fmul_rn(dy, H_), cy);
        float pw = __fmul_rn((float)exp((double)dw), W_);
        float ph = __fmul_rn((float)exp((double)dh), H_);
        float hw = __fmul_rn(0.5f, pw), hh = __fmul_rn(0.5f, ph);
        float x1 = __fsub_rn(px, hw), y1 = __fsub_rn(py, hh);
        float x2 = __fadd_rn(px, hw), y2 = __fadd_rn(py, hh);
        x1 = fminf(fmaxf(x1, 0.0f), maxx);
        y1 = fminf(fmaxf(y1, 0.0f), maxy);
        x2 = fminf(fmaxf(x2, 0.0f), maxx);
        y2 = fminf(fmaxf(y2, 0.0f), maxy);
        props[(size_t)b * PRE_K + r] = make_float4(x1, y1, x2, y2);
    }
}

// ---------- fused on-demand NMS: IoU vs kept only + in-tile greedy, 8 blocks ----------
__global__ __launch_bounds__(1024) void nms_kernel(const float4* __restrict__ props,
                                                   float* __restrict__ out) {
    __shared__ float4 sbox[PRE_K];                 // 32000 B
    __shared__ float4 kbox[POST_K];                // 4800 B
    __shared__ unsigned long long colpart[16][64]; // 8192 B
    __shared__ unsigned long long deadmask[16];    // 128 B
    __shared__ int ctl[2];                         // [0]=total kept  [1]=done
    int b = blockIdx.x, tid = threadIdx.x;
    int jl = tid & 63, w = tid >> 6;
    for (int t = tid; t < PRE_K; t += 1024) sbox[t] = props[(size_t)b * PRE_K + t];
    if (tid == 0) { ctl[0] = 0; ctl[1] = 0; }
    __syncthreads();
    for (int k = 0; k < 32; ++k) {
        int j = k * 64 + jl;
        bool jvalid = j < PRE_K;
        float4 jb = jvalid ? sbox[j] : make_float4(0.f, 0.f, -1.f, -1.f);
        float barea = __fmul_rn(__fsub_rn(jb.z, jb.x), __fsub_rn(jb.w, jb.y));
        int T = ctl[0];
        // dead via previously-kept boxes (strided over 16 waves)
        bool dead = false;
        if (jvalid) {
            for (int i = w; i < T; i += 16) {
                if (iou_gt(kbox[i], jb, barea)) { dead = true; break; }
            }
        }
        deadmask[w] = __ballot(dead);
        // in-tile column mask: wave w computes suppressor bits ii in [4w, 4w+4)
        unsigned long long part = 0ULL;
        if (jvalid) {
#pragma unroll
            for (int q = 0; q < 4; ++q) {
                int ii = 4 * w + q;
                if (ii < jl) {
                    if (iou_gt(sbox[k * 64 + ii], jb, barea)) part |= (1ULL << ii);
                }
            }
        }
        colpart[w][jl] = part;
        __syncthreads();
        if (w == 0) {
            unsigned long long d = deadmask[0];
            unsigned long long diag = colpart[0][jl];
#pragma unroll
            for (int x = 1; x < 16; ++x) { d |= deadmask[x]; diag |= colpart[x][jl]; }
            bool mydead = ((d >> jl) & 1ULL) != 0ULL;
            unsigned long long alive = __ballot(!mydead && jvalid);
            unsigned long long keptw = 0ULL;
            int total = ctl[0];
            int done = 0;
            while (alive) {
                int i = __builtin_ctzll(alive);
                keptw |= (1ULL << i);
                if (jl == 0 && total < POST_K) kbox[total] = sbox[k * 64 + i];
                total++;
                if (total >= POST_K) { done = 1; break; }
                unsigned long long sup = __ballot(((diag >> i) & 1ULL) != 0ULL);
                alive &= ~sup;
                alive &= ~keptw;
            }
            if (jl == 0) { ctl[0] = total; ctl[1] = done; }
        }
        __syncthreads();
        if (ctl[1]) break;
    }
    __syncthreads();
    int K = min(ctl[0], POST_K);
    for (int r = tid; r < POST_K; r += 1024) {
        float4 v = make_float4(0.f, 0.f, 0.f, 0.f);
        if (r < K) v = kbox[r];
        float* o = out + ((size_t)b * POST_K + r) * 5;
        o[0] = (float)b;
        o[1] = v.x;
        o[2] = v.y;
        o[3] = v.z;
        o[4] = v.w;
    }
}

// ---------------- launcher ----------------
extern "C" void kernel_launch(void* const* d_in, const int* in_sizes, int n_in,
                              void* d_out, int out_size, void* d_ws, size_t ws_size,
                              hipStream_t stream) {
    const float* scores = (const float*)d_in[0];
    const float* deltas = (const float*)d_in[1];
    const float* im_info = (const float*)d_in[2];
    float* out = (float*)d_out;
    char* ws = (char*)d_ws;

    // workspace layout (bytes)
    unsigned int* h0out = (unsigned int*)(ws + 0);                 // 144*2048*4 = 1179648
    unsigned int* gh1 = (unsigned int*)(ws + 1179648);             // 4096
    uint2* state0 = (uint2*)(ws + 1183744);                        // 64
    int* cnt = (int*)(ws + 1183808);                               // 64
    unsigned long long* buf = (unsigned long long*)(ws + 1183872); // 8*8192*8 = 524288
    float4* props = (float4*)(ws + 1708160);                       // 8*2000*16 = 256000
    // total ≈ 1.96 MB; select0 zeroes gh1+cnt; everything else written before read

    hipLaunchKernelGGL(hist0_kernel, dim3(PARTS, NB), dim3(1024), 0, stream, scores, h0out);
    hipLaunchKernelGGL(select0_kernel, dim3(NB), dim3(1024), 0, stream, h0out, state0, gh1, cnt);
    hipLaunchKernelGGL(gatherc_kernel, dim3(PARTS, NB), dim3(1024), 0, stream,
                       scores, state0, gh1, cnt, buf);
    hipLaunchKernelGGL(sortdec_kernel, dim3(NB), dim3(1024), 0, stream,
                       buf, cnt, state0, gh1, deltas, im_info, props);
    hipLaunchKernelGGL(nms_kernel, dim3(NB), dim3(1024), 0, stream, props, out);
}